// Round 6
// baseline (213.179 us; speedup 1.0000x reference)
//
#include <hip/hip_runtime.h>

// YOLO loss: preds/targets (N,7,7,30) fp32 -> scalar.
// Memory-bound streaming reduction: 192.7 MB logical read.
//
// R7: NO LDS AT ALL. R0..R6 (five schedules: gload_lds+barrier, persistent
// counted-vmcnt gload_lds, reg-staged 256-thr, no-spill reg-staged,
// barrier-free persistent 1-wave) ALL plateau at 69-75 us (2.75 TB/s logical
// read; HBM fetch only 1.3 TB/s = 20% of achievable -- NOT a BW roofline).
// R3's spilling variant proved the machine sustains ~3.8 TB/s logical read +
// 1.9 TB/s write IN THIS CONTEXT (its spill ops were independent, un-chained).
// Common poison in all five: the global->LDS->register round-trip, whose
// vmcnt/lgkmcnt dependency chains cap effective per-wave MLP at a few loads.
// Fix: each lane owns TWO consecutive cells (240 B = 15 aligned float4 per
// tensor), so a wave issues 30 fully INDEPENDENT global_load_dwordx4 (30 KB
// in flight/wave), zero ds ops, zero barriers, zero cross-lane. Unpack with
// static indices (no scratch), run cell_loss twice, grid-stride persistent.

#define SGRID 7
#define DDIM 30
#define NCLS 20
#define LAMBDA_NOOBJ 0.5f
#define IOU_EPS 1e-10f

#define THREADS 64     // one wave per block
#define GRIDB 3072     // 12 waves/CU * 256 CU; persistent grid-stride

__device__ __forceinline__ float cell_loss(const float* pv, const float* tv) {
    float loss = 0.0f;

    // IoU per box (center format).
    float iou0, iou1;
#pragma unroll
    for (int b = 0; b < 2; ++b) {
        const float x1 = pv[b * 5 + 0], y1 = pv[b * 5 + 1];
        const float w1 = pv[b * 5 + 2], h1 = pv[b * 5 + 3];
        const float x2 = tv[b * 5 + 0], y2 = tv[b * 5 + 1];
        const float w2 = tv[b * 5 + 2], h2 = tv[b * 5 + 3];
        float iw = fminf(x1 + 0.5f * w1, x2 + 0.5f * w2) -
                   fmaxf(x1 - 0.5f * w1, x2 - 0.5f * w2);
        iw = fmaxf(iw, 0.0f);
        float ih = fminf(y1 + 0.5f * h1, y2 + 0.5f * h2) -
                   fmaxf(y1 - 0.5f * h1, y2 - 0.5f * h2);
        ih = fmaxf(ih, 0.0f);
        const float inter = iw * ih;
        const float uni = w1 * h1 + w2 * h2 - inter;
        const float iou = inter / (uni + IOU_EPS);
        if (b == 0) iou0 = iou; else iou1 = iou;
    }

    // argmax ties -> first index (box 0).
    const bool sel1 = iou1 > iou0;

    // coord loss (selected box x,y), gated by has_obj = targets[...,4] > 0.
    {
        const float px = sel1 ? pv[5] : pv[0];
        const float py = sel1 ? pv[6] : pv[1];
        const float tx = sel1 ? tv[5] : tv[0];
        const float ty = sel1 ? tv[6] : tv[1];
        const float dx = px - tx, dy = py - ty;
        if (tv[4] > 0.0f) loss += dx * dx + dy * dy;
    }

    // class SSE + running argmax of target class (ties -> first);
    // track pc_gt by value to avoid dynamic register indexing.
    float gt_val = tv[10];
    float pc_gt = pv[10];
#pragma unroll
    for (int j = 0; j < NCLS; ++j) {
        const float pc = pv[10 + j], tc = tv[10 + j];
        const float d = pc - tc;
        loss += d * d;
        const bool gm = tc > gt_val;
        gt_val = gm ? tc : gt_val;
        pc_gt = gm ? pc : pc_gt;
    }

    // conf loss: w_b * (iou_b * pc_gt - iou_b)^2 = w_b * iou_b^2 * (pc_gt-1)^2
    const float c = pc_gt - 1.0f;
    const float d0 = iou0 * c, d1 = iou1 * c;
    const float w0 = sel1 ? LAMBDA_NOOBJ : 1.0f;
    const float w1 = sel1 ? 1.0f : LAMBDA_NOOBJ;
    loss += w0 * d0 * d0 + w1 * d1 * d1;
    return loss;
}

__global__ __launch_bounds__(THREADS) void yolo_loss_main(
    const float* __restrict__ preds, const float* __restrict__ targets,
    float* __restrict__ partials, int n_cells) {
    const int gthreads = GRIDB * THREADS;
    const int gtid = blockIdx.x * THREADS + threadIdx.x;
    const int npairs = n_cells >> 1;  // 2 cells per lane per iteration
    float loss = 0.0f;

    for (int p = gtid; p < npairs; p += gthreads) {
        // Pair base: 2 cells * 30 floats = 60 floats = 240 B, 16B-aligned.
        const float4* pb = (const float4*)(preds + (long long)p * 60);
        const float4* tb = (const float4*)(targets + (long long)p * 60);

        // 30 fully independent dwordx4 loads -- the whole point. Static
        // array indices (full unroll) keep P/T in registers; the compiler
        // issues all loads then consumes with counted vmcnt as data lands.
        float4 P[15], T[15];
#pragma unroll
        for (int k = 0; k < 15; ++k) P[k] = pb[k];
#pragma unroll
        for (int k = 0; k < 15; ++k) T[k] = tb[k];

        // Static unpack: pv/tv are pure register aliases of P/T components.
        float pv[60], tv[60];
#pragma unroll
        for (int k = 0; k < 15; ++k) {
            pv[4 * k + 0] = P[k].x; pv[4 * k + 1] = P[k].y;
            pv[4 * k + 2] = P[k].z; pv[4 * k + 3] = P[k].w;
            tv[4 * k + 0] = T[k].x; tv[4 * k + 1] = T[k].y;
            tv[4 * k + 2] = T[k].z; tv[4 * k + 3] = T[k].w;
        }

        loss += cell_loss(pv, tv);
        loss += cell_loss(pv + 30, tv + 30);  // static offsets after inline
    }

    // Odd-cell tail (zero at bench shape: n_cells = N*49, N even).
    if ((n_cells & 1) && gtid == 0) {
        const long long cb = (long long)(n_cells - 1) * DDIM;
        float pv[DDIM], tv[DDIM];
        const float2* p2 = (const float2*)(preds + cb);   // 120B stride -> 8B-aligned
        const float2* t2 = (const float2*)(targets + cb);
#pragma unroll
        for (int i = 0; i < DDIM / 2; ++i) {
            ((float2*)pv)[i] = p2[i];
            ((float2*)tv)[i] = t2[i];
        }
        loss += cell_loss(pv, tv);
    }

    // Wave-level reduction (block == one wave), one store per block.
#pragma unroll
    for (int off = 32; off > 0; off >>= 1) loss += __shfl_down(loss, off, 64);
    if (threadIdx.x == 0) partials[blockIdx.x] = loss;
}

#define RTHREADS 1024
__global__ __launch_bounds__(RTHREADS) void yolo_loss_reduce(
    const float* __restrict__ partials, int n, float inv_n,
    float* __restrict__ out) {
    __shared__ float red[RTHREADS / 64];
    float v = 0.0f;
    for (int i = threadIdx.x; i < n; i += RTHREADS) v += partials[i];
#pragma unroll
    for (int off = 32; off > 0; off >>= 1) v += __shfl_down(v, off, 64);
    if ((threadIdx.x & 63) == 0) red[threadIdx.x >> 6] = v;
    __syncthreads();
    if (threadIdx.x == 0) {
        float s = 0.0f;
#pragma unroll
        for (int w = 0; w < RTHREADS / 64; ++w) s += red[w];
        out[0] = s * inv_n;
    }
}

extern "C" void kernel_launch(void* const* d_in, const int* in_sizes, int n_in,
                              void* d_out, int out_size, void* d_ws, size_t ws_size,
                              hipStream_t stream) {
    const float* preds = (const float*)d_in[0];
    const float* targets = (const float*)d_in[1];
    float* out = (float*)d_out;

    const int total = in_sizes[0];                        // N*S*S*D elements
    const int n_cells = total / DDIM;                     // N*S*S (802816)
    const int N = total / (SGRID * SGRID * DDIM);         // 16384

    float* partials = (float*)d_ws;  // GRIDB floats; every block writes once

    yolo_loss_main<<<GRIDB, THREADS, 0, stream>>>(preds, targets, partials, n_cells);
    yolo_loss_reduce<<<1, RTHREADS, 0, stream>>>(partials, GRIDB, 1.0f / (float)N, out);
}